// Round 7
// baseline (204.975 us; speedup 1.0000x reference)
//
#include <hip/hip_runtime.h>

#define B_TOT 8192
#define PP 32
#define QQ 32
#define RR 8
#define H1 128
#define H2 64
#define PHH 16
#define PAIRS 1024
#define OUT_UNITS 8192

#define NBLK_IA 4096   // interact-role blocks: (64 b-tiles of 128) x (64 pp-groups)
#define NBLK_MM 512    // main-role blocks: 128 btiles x 2 hf x 2 which

typedef float f32x16 __attribute__((ext_vector_type(16)));
typedef short s16x8  __attribute__((ext_vector_type(8)));

union FragU { s16x8 v; unsigned int u[4]; };

// pack hi16(lo),hi16(hi) -> one dword (bf16 truncation), element 2*d = lo
__device__ inline unsigned int pack_bf16(float lo, float hi) {
    return __builtin_amdgcn_perm(__float_as_uint(hi), __float_as_uint(lo), 0x07060302u);
}

// LDS: ia.staging and ia.red alias (staging dead after K-loop, barrier-protected).
// mm.h1T is half-size (phase A/B split into two j-halves). Union = 17.7 KB
// -> 8 blocks/CU (R6 lesson: 34 KB -> 4 blocks/CU left 51% of cycles stalled).
union SharedU {
    union {
        struct {
            float zT[16][128];
            float4 lwx[16][2];
            float4 lwz[16][2];
            float4 lhb[16][2];
            unsigned lpw1[16][4][16];
            float lpb[16][16];
            float lpw2[16][16];
        } s;                          // 15872 B
        float red[128][33];           // 16896 B
    } ia;
    struct {
        float h1T[64][65];            // 16640 B
        float red2[4][64];
    } mm;                             // 17664 B
};

// Fused kernel. Blocks [0,512): main-effect MLPs (dispatched first so their
// latency-bound scalar loads overlap the ia bulk). Blocks [512,4608):
// interaction via MFMA 32x32x16 bf16 (wave = 64 batches = 2 tiles sharing
// B-frag, 4 pps each; pb1 folded into MFMA C operand).
__global__ __launch_bounds__(256, 6) void fused_k(
    const float* __restrict__ x, const float* __restrict__ z,
    const float* __restrict__ xw1, const float* __restrict__ xb1,
    const float* __restrict__ xw2, const float* __restrict__ xb2,
    const float* __restrict__ xw3, const float* __restrict__ xb3,
    const float* __restrict__ zw1, const float* __restrict__ zb1,
    const float* __restrict__ zw2, const float* __restrict__ zb2,
    const float* __restrict__ zw3, const float* __restrict__ zb3,
    const float* __restrict__ xzw, const float* __restrict__ xzb,
    const float* __restrict__ pw1, const float* __restrict__ pb1,
    const float* __restrict__ pw2, float* __restrict__ out)
{
    __shared__ SharedU sh;
    const int bid  = blockIdx.x;
    const int t    = threadIdx.x;
    const int w    = t >> 6;
    const int lane = t & 63;

    if (bid >= NBLK_MM) {
        // ------------------------- interaction role -------------------------
        const int ib    = bid - NBLK_MM;
        const int bx    = ib & 63;
        const int y     = ib >> 6;
        const int m     = lane & 31;     // batch row within tile
        const int kh    = lane >> 5;     // A k-half / pair selector
        const int jj    = m & 15;        // j within column's pair
        const int cph   = m >> 4;        // column's pair selector
        const int b0    = bx * 128;
        const int i_x   = y >> 1;        // shared x-feature of the 16 pairs
        const int k0    = (y & 1) * 16;  // z-feature base
        const int pair0 = y * 16;

        // stage zT: 128 batches x 16 z-features (transposed)
        {
            int row = t >> 1;
            int c8  = (t & 1) * 8;
            const float* src = z + (size_t)(b0 + row) * 32 + k0 + c8;
            float4 a4 = *reinterpret_cast<const float4*>(src);
            float4 b4 = *reinterpret_cast<const float4*>(src + 4);
            sh.ia.s.zT[c8+0][row] = a4.x; sh.ia.s.zT[c8+1][row] = a4.y;
            sh.ia.s.zT[c8+2][row] = a4.z; sh.ia.s.zT[c8+3][row] = a4.w;
            sh.ia.s.zT[c8+4][row] = b4.x; sh.ia.s.zT[c8+5][row] = b4.y;
            sh.ia.s.zT[c8+6][row] = b4.z; sh.ia.s.zT[c8+7][row] = b4.w;
        }
        // stage h-layer weights (coalesced)
        if (t < 128) {
            int p = t >> 3, c = t & 7;
            int gp = pair0 + p;
            reinterpret_cast<float*>(sh.ia.s.lwx)[t] = xzw[(size_t)i_x * OUT_UNITS + gp*8 + c];
            reinterpret_cast<float*>(sh.ia.s.lwz)[t] = xzw[(size_t)(32 + k0 + p) * OUT_UNITS + gp*8 + c];
            reinterpret_cast<float*>(sh.ia.s.lhb)[t] = xzb[gp*8 + c];
        }
        // stage pb1 / pw2
        {
            int p = t >> 4, j = t & 15;
            int gp = pair0 + p;
            sh.ia.s.lpb[p][j]  = pb1[gp*PHH + j];
            sh.ia.s.lpw2[p][j] = pw2[gp*PHH + j];
        }
        // stage pw1 pre-packed to bf16
        #pragma unroll
        for (int it = 0; it < 4; ++it) {
            int idx = t + it * 256;
            int p = idx >> 6, u = (idx >> 4) & 3, j = idx & 15;
            int gp = pair0 + p;
            float lo = pw1[(size_t)gp * 128 + (2*u)*16 + j];
            float hi = pw1[(size_t)gp * 128 + (2*u+1)*16 + j];
            sh.ia.s.lpw1[p][u][j] = pack_bf16(lo, hi);
        }

        const int bl = (w & 1) * 64 + m;
        const float xv0 = x[(size_t)(b0 + bl)      * 32 + i_x];
        const float xv1 = x[(size_t)(b0 + bl + 32) * 32 + i_x];
        __syncthreads();

        f32x16 acc0, acc1;
        #pragma unroll
        for (int r = 0; r < 16; ++r) { acc0[r] = 0.f; acc1[r] = 0.f; }

        const bool realB = (kh == cph);
        const int  ppl0  = (w >> 1) * 4;

        #pragma unroll 2
        for (int kk = 0; kk < 4; ++kk) {
            const int ppl = ppl0 + kk;
            const int pAl = 2*ppl + kh;
            const int pBl = 2*ppl + cph;

            const float zv0 = sh.ia.s.zT[pAl][bl];
            const float zv1 = sh.ia.s.zT[pAl][bl + 32];
            const float4 wxa = sh.ia.s.lwx[pAl][0], wxb = sh.ia.s.lwx[pAl][1];
            const float4 wza = sh.ia.s.lwz[pAl][0], wzb = sh.ia.s.lwz[pAl][1];
            const float4 hba = sh.ia.s.lhb[pAl][0], hbb = sh.ia.s.lhb[pAl][1];

            float h0[8], h1v[8];
            h0[0] = fmaxf(fmaf(xv0, wxa.x, fmaf(zv0, wza.x, hba.x)), 0.f);
            h0[1] = fmaxf(fmaf(xv0, wxa.y, fmaf(zv0, wza.y, hba.y)), 0.f);
            h0[2] = fmaxf(fmaf(xv0, wxa.z, fmaf(zv0, wza.z, hba.z)), 0.f);
            h0[3] = fmaxf(fmaf(xv0, wxa.w, fmaf(zv0, wza.w, hba.w)), 0.f);
            h0[4] = fmaxf(fmaf(xv0, wxb.x, fmaf(zv0, wzb.x, hbb.x)), 0.f);
            h0[5] = fmaxf(fmaf(xv0, wxb.y, fmaf(zv0, wzb.y, hbb.y)), 0.f);
            h0[6] = fmaxf(fmaf(xv0, wxb.z, fmaf(zv0, wzb.z, hbb.z)), 0.f);
            h0[7] = fmaxf(fmaf(xv0, wxb.w, fmaf(zv0, wzb.w, hbb.w)), 0.f);
            h1v[0] = fmaxf(fmaf(xv1, wxa.x, fmaf(zv1, wza.x, hba.x)), 0.f);
            h1v[1] = fmaxf(fmaf(xv1, wxa.y, fmaf(zv1, wza.y, hba.y)), 0.f);
            h1v[2] = fmaxf(fmaf(xv1, wxa.z, fmaf(zv1, wza.z, hba.z)), 0.f);
            h1v[3] = fmaxf(fmaf(xv1, wxa.w, fmaf(zv1, wza.w, hba.w)), 0.f);
            h1v[4] = fmaxf(fmaf(xv1, wxb.x, fmaf(zv1, wzb.x, hbb.x)), 0.f);
            h1v[5] = fmaxf(fmaf(xv1, wxb.y, fmaf(zv1, wzb.y, hbb.y)), 0.f);
            h1v[6] = fmaxf(fmaf(xv1, wxb.z, fmaf(zv1, wzb.z, hbb.z)), 0.f);
            h1v[7] = fmaxf(fmaf(xv1, wxb.w, fmaf(zv1, wzb.w, hbb.w)), 0.f);

            FragU a0, a1, bf;
            a0.u[0] = pack_bf16(h0[0], h0[1]);
            a0.u[1] = pack_bf16(h0[2], h0[3]);
            a0.u[2] = pack_bf16(h0[4], h0[5]);
            a0.u[3] = pack_bf16(h0[6], h0[7]);
            a1.u[0] = pack_bf16(h1v[0], h1v[1]);
            a1.u[1] = pack_bf16(h1v[2], h1v[3]);
            a1.u[2] = pack_bf16(h1v[4], h1v[5]);
            a1.u[3] = pack_bf16(h1v[6], h1v[7]);
            bf.u[0] = realB ? sh.ia.s.lpw1[pBl][0][jj] : 0u;
            bf.u[1] = realB ? sh.ia.s.lpw1[pBl][1][jj] : 0u;
            bf.u[2] = realB ? sh.ia.s.lpw1[pBl][2][jj] : 0u;
            bf.u[3] = realB ? sh.ia.s.lpw1[pBl][3][jj] : 0u;

            const float pbv = sh.ia.s.lpb[pBl][jj];
            const float w2v = sh.ia.s.lpw2[pBl][jj];

            f32x16 cpb;
            #pragma unroll
            for (int r = 0; r < 16; ++r) cpb[r] = pbv;

            f32x16 d0 = __builtin_amdgcn_mfma_f32_32x32x16_bf16(a0.v, bf.v, cpb, 0, 0, 0);
            f32x16 d1 = __builtin_amdgcn_mfma_f32_32x32x16_bf16(a1.v, bf.v, cpb, 0, 0, 0);

            #pragma unroll
            for (int r = 0; r < 16; ++r)
                acc0[r] = fmaf(fmaxf(d0[r], 0.f), w2v, acc0[r]);
            #pragma unroll
            for (int r = 0; r < 16; ++r)
                acc1[r] = fmaf(fmaxf(d1[r], 0.f), w2v, acc1[r]);
        }

        __syncthreads();   // staging LDS dead; red aliases it from here on
        // phased reduction: waves 0,1 write; waves 2,3 accumulate
        const int rb0 = (w & 1) * 64;
        if (w < 2) {
            #pragma unroll
            for (int r = 0; r < 16; ++r) {
                int rowf = (r & 3) + 8 * (r >> 2) + 4 * kh;
                sh.ia.red[rb0 + rowf][m]      = acc0[r];
                sh.ia.red[rb0 + 32 + rowf][m] = acc1[r];
            }
        }
        __syncthreads();
        if (w >= 2) {
            #pragma unroll
            for (int r = 0; r < 16; ++r) {
                int rowf = (r & 3) + 8 * (r >> 2) + 4 * kh;
                sh.ia.red[rb0 + rowf][m]      += acc0[r];
                sh.ia.red[rb0 + 32 + rowf][m] += acc1[r];
            }
        }
        __syncthreads();
        if (t < 128) {
            float s = 0.f;
            #pragma unroll
            for (int c = 0; c < 32; ++c) s += sh.ia.red[t][c];
            atomicAdd(out + b0 + t, s);
        }
    } else {
        // --------------------------- main-MLP role ---------------------------
        const int r2    = bid;
        const int btile = r2 & 127;
        const int hf    = (r2 >> 7) & 1;
        const int which = (r2 >> 8) & 1;
        const float* in = which ? z   : x;
        const float* w1 = which ? zw1 : xw1;
        const float* b1 = which ? zb1 : xb1;
        const float* w2 = which ? zw2 : xw2;
        const float* b2 = which ? zb2 : xb2;
        const float* w3 = which ? zw3 : xw3;
        const float* b3 = which ? zb3 : xb3;

        const int wu = __builtin_amdgcn_readfirstlane(w);
        const int b0 = btile * 64;

        // input row in registers
        float xr[32];
        const float4* xrp = reinterpret_cast<const float4*>(in + (size_t)(b0 + lane) * 32);
        #pragma unroll
        for (int q = 0; q < 8; ++q) {
            float4 v = xrp[q];
            xr[4*q] = v.x; xr[4*q+1] = v.y; xr[4*q+2] = v.z; xr[4*q+3] = v.w;
        }

        const int n0 = __builtin_amdgcn_readfirstlane(hf*32 + wu*8);
        float h2[8];
        #pragma unroll
        for (int n = 0; n < 8; ++n) h2[n] = b2[n0 + n];

        // two j-halves: phase A computes 16 j per wave, phase B consumes
        #pragma unroll
        for (int half = 0; half < 2; ++half) {
            const int j0 = half*64 + wu*16;
            float h1[16];
            #pragma unroll
            for (int j = 0; j < 16; ++j) h1[j] = b1[j0 + j];
            #pragma unroll
            for (int mm = 0; mm < 32; ++mm) {
                float xv = xr[mm];
                #pragma unroll
                for (int j = 0; j < 16; ++j)
                    h1[j] = fmaf(xv, w1[mm*H1 + j0 + j], h1[j]);
            }
            __syncthreads();   // protect h1T reuse from previous half's reads
            #pragma unroll
            for (int j = 0; j < 16; ++j)
                sh.mm.h1T[wu*16 + j][lane] = fmaxf(h1[j], 0.f);
            __syncthreads();
            #pragma unroll 4
            for (int mm = 0; mm < 64; ++mm) {
                float hv = sh.mm.h1T[mm][lane];
                #pragma unroll
                for (int n = 0; n < 8; ++n)
                    h2[n] = fmaf(hv, w2[(half*64 + mm)*H2 + n0 + n], h2[n]);
            }
        }
        float p = 0.f;
        #pragma unroll
        for (int n = 0; n < 8; ++n)
            p = fmaf(fmaxf(h2[n], 0.f), w3[n0 + n], p);

        sh.mm.red2[wu][lane] = p;
        __syncthreads();
        if (wu == 0) {
            float s = sh.mm.red2[0][lane] + sh.mm.red2[1][lane]
                    + sh.mm.red2[2][lane] + sh.mm.red2[3][lane];
            if (hf == 0) s += b3[0];
            atomicAdd(out + b0 + lane, s);
        }
    }
}

extern "C" void kernel_launch(void* const* d_in, const int* in_sizes, int n_in,
                              void* d_out, int out_size, void* d_ws, size_t ws_size,
                              hipStream_t stream) {
    const float* x   = (const float*)d_in[0];
    const float* z   = (const float*)d_in[1];
    const float* xw1 = (const float*)d_in[2];
    const float* xb1 = (const float*)d_in[3];
    const float* xw2 = (const float*)d_in[4];
    const float* xb2 = (const float*)d_in[5];
    const float* xw3 = (const float*)d_in[6];
    const float* xb3 = (const float*)d_in[7];
    const float* zw1 = (const float*)d_in[8];
    const float* zb1 = (const float*)d_in[9];
    const float* zw2 = (const float*)d_in[10];
    const float* zb2 = (const float*)d_in[11];
    const float* zw3 = (const float*)d_in[12];
    const float* zb3 = (const float*)d_in[13];
    const float* xzw = (const float*)d_in[14];
    const float* xzb = (const float*)d_in[15];
    const float* pw1 = (const float*)d_in[16];
    const float* pb1 = (const float*)d_in[17];
    const float* pw2 = (const float*)d_in[18];
    float* out = (float*)d_out;

    hipMemsetAsync(out, 0, (size_t)out_size * sizeof(float), stream);

    fused_k<<<dim3(NBLK_IA + NBLK_MM), 256, 0, stream>>>(
        x, z, xw1, xb1, xw2, xb2, xw3, xb3,
        zw1, zb1, zw2, zb2, zw3, zb3,
        xzw, xzb, pw1, pb1, pw2, out);
}

// Round 8
// 127.954 us; speedup vs baseline: 1.6019x; 1.6019x over previous
//
#include <hip/hip_runtime.h>

#define B_TOT 8192
#define PP 32
#define QQ 32
#define RR 8
#define H1 128
#define H2 64
#define PHH 16
#define PAIRS 1024
#define OUT_UNITS 8192

#define NBLK_IA 4096   // interact-role blocks: (64 b-tiles of 128) x (64 pp-groups)
#define NBLK_MM 512    // main-role blocks: 128 btiles x 2 hf x 2 which

typedef float f32x16 __attribute__((ext_vector_type(16)));
typedef short s16x8  __attribute__((ext_vector_type(8)));

union FragU { s16x8 v; unsigned int u[4]; };

// pack hi16(lo),hi16(hi) -> one dword (bf16 truncation), element 2*d = lo
__device__ inline unsigned int pack_bf16(float lo, float hi) {
    return __builtin_amdgcn_perm(__float_as_uint(hi), __float_as_uint(lo), 0x07060302u);
}

// LDS: ia.staging and ia.red alias (staging dead after K-loop, barrier-protected).
// mm.h1T is half-size (phase A/B split into two j-halves). Union = 17.7 KB.
// R7 lesson: __launch_bounds__ min-waves=6 squeezed VGPR budget to 84 and the
// compiler SPILLED the MFMA accumulators to scratch (WRITE_SIZE 2->365 MB).
// Keep min-waves=4 (budget 128); VGPR ~60 lets HW reach 8 waves/SIMD anyway.
union SharedU {
    union {
        struct {
            float zT[16][128];
            float4 lwx[16][2];
            float4 lwz[16][2];
            float4 lhb[16][2];
            unsigned lpw1[16][4][16];
            float lpb[16][16];
            float lpw2[16][16];
        } s;                          // 15872 B
        float red[128][33];           // 16896 B
    } ia;
    struct {
        float h1T[64][65];            // 16640 B
        float red2[4][64];
    } mm;                             // 17664 B
};

// Fused kernel. Blocks [0,512): main-effect MLPs (dispatched first so their
// latency-bound scalar loads overlap the ia bulk). Blocks [512,4608):
// interaction via MFMA 32x32x16 bf16 (wave = 64 batches = 2 tiles sharing
// B-frag, 4 pps each; pb1 folded into MFMA C operand).
__global__ __launch_bounds__(256, 4) void fused_k(
    const float* __restrict__ x, const float* __restrict__ z,
    const float* __restrict__ xw1, const float* __restrict__ xb1,
    const float* __restrict__ xw2, const float* __restrict__ xb2,
    const float* __restrict__ xw3, const float* __restrict__ xb3,
    const float* __restrict__ zw1, const float* __restrict__ zb1,
    const float* __restrict__ zw2, const float* __restrict__ zb2,
    const float* __restrict__ zw3, const float* __restrict__ zb3,
    const float* __restrict__ xzw, const float* __restrict__ xzb,
    const float* __restrict__ pw1, const float* __restrict__ pb1,
    const float* __restrict__ pw2, float* __restrict__ out)
{
    __shared__ SharedU sh;
    const int bid  = blockIdx.x;
    const int t    = threadIdx.x;
    const int w    = t >> 6;
    const int lane = t & 63;

    if (bid >= NBLK_MM) {
        // ------------------------- interaction role -------------------------
        const int ib    = bid - NBLK_MM;
        const int bx    = ib & 63;
        const int y     = ib >> 6;
        const int m     = lane & 31;     // batch row within tile
        const int kh    = lane >> 5;     // A k-half / pair selector
        const int jj    = m & 15;        // j within column's pair
        const int cph   = m >> 4;        // column's pair selector
        const int b0    = bx * 128;
        const int i_x   = y >> 1;        // shared x-feature of the 16 pairs
        const int k0    = (y & 1) * 16;  // z-feature base
        const int pair0 = y * 16;

        // stage zT: 128 batches x 16 z-features (transposed)
        {
            int row = t >> 1;
            int c8  = (t & 1) * 8;
            const float* src = z + (size_t)(b0 + row) * 32 + k0 + c8;
            float4 a4 = *reinterpret_cast<const float4*>(src);
            float4 b4 = *reinterpret_cast<const float4*>(src + 4);
            sh.ia.s.zT[c8+0][row] = a4.x; sh.ia.s.zT[c8+1][row] = a4.y;
            sh.ia.s.zT[c8+2][row] = a4.z; sh.ia.s.zT[c8+3][row] = a4.w;
            sh.ia.s.zT[c8+4][row] = b4.x; sh.ia.s.zT[c8+5][row] = b4.y;
            sh.ia.s.zT[c8+6][row] = b4.z; sh.ia.s.zT[c8+7][row] = b4.w;
        }
        // stage h-layer weights (coalesced)
        if (t < 128) {
            int p = t >> 3, c = t & 7;
            int gp = pair0 + p;
            reinterpret_cast<float*>(sh.ia.s.lwx)[t] = xzw[(size_t)i_x * OUT_UNITS + gp*8 + c];
            reinterpret_cast<float*>(sh.ia.s.lwz)[t] = xzw[(size_t)(32 + k0 + p) * OUT_UNITS + gp*8 + c];
            reinterpret_cast<float*>(sh.ia.s.lhb)[t] = xzb[gp*8 + c];
        }
        // stage pb1 / pw2
        {
            int p = t >> 4, j = t & 15;
            int gp = pair0 + p;
            sh.ia.s.lpb[p][j]  = pb1[gp*PHH + j];
            sh.ia.s.lpw2[p][j] = pw2[gp*PHH + j];
        }
        // stage pw1 pre-packed to bf16
        #pragma unroll
        for (int it = 0; it < 4; ++it) {
            int idx = t + it * 256;
            int p = idx >> 6, u = (idx >> 4) & 3, j = idx & 15;
            int gp = pair0 + p;
            float lo = pw1[(size_t)gp * 128 + (2*u)*16 + j];
            float hi = pw1[(size_t)gp * 128 + (2*u+1)*16 + j];
            sh.ia.s.lpw1[p][u][j] = pack_bf16(lo, hi);
        }

        const int bl = (w & 1) * 64 + m;
        const float xv0 = x[(size_t)(b0 + bl)      * 32 + i_x];
        const float xv1 = x[(size_t)(b0 + bl + 32) * 32 + i_x];
        __syncthreads();

        f32x16 acc0, acc1;
        #pragma unroll
        for (int r = 0; r < 16; ++r) { acc0[r] = 0.f; acc1[r] = 0.f; }

        const bool realB = (kh == cph);
        const int  ppl0  = (w >> 1) * 4;

        #pragma unroll 2
        for (int kk = 0; kk < 4; ++kk) {
            const int ppl = ppl0 + kk;
            const int pAl = 2*ppl + kh;
            const int pBl = 2*ppl + cph;

            const float zv0 = sh.ia.s.zT[pAl][bl];
            const float zv1 = sh.ia.s.zT[pAl][bl + 32];
            const float4 wxa = sh.ia.s.lwx[pAl][0], wxb = sh.ia.s.lwx[pAl][1];
            const float4 wza = sh.ia.s.lwz[pAl][0], wzb = sh.ia.s.lwz[pAl][1];
            const float4 hba = sh.ia.s.lhb[pAl][0], hbb = sh.ia.s.lhb[pAl][1];

            float h0[8], h1v[8];
            h0[0] = fmaxf(fmaf(xv0, wxa.x, fmaf(zv0, wza.x, hba.x)), 0.f);
            h0[1] = fmaxf(fmaf(xv0, wxa.y, fmaf(zv0, wza.y, hba.y)), 0.f);
            h0[2] = fmaxf(fmaf(xv0, wxa.z, fmaf(zv0, wza.z, hba.z)), 0.f);
            h0[3] = fmaxf(fmaf(xv0, wxa.w, fmaf(zv0, wza.w, hba.w)), 0.f);
            h0[4] = fmaxf(fmaf(xv0, wxb.x, fmaf(zv0, wzb.x, hbb.x)), 0.f);
            h0[5] = fmaxf(fmaf(xv0, wxb.y, fmaf(zv0, wzb.y, hbb.y)), 0.f);
            h0[6] = fmaxf(fmaf(xv0, wxb.z, fmaf(zv0, wzb.z, hbb.z)), 0.f);
            h0[7] = fmaxf(fmaf(xv0, wxb.w, fmaf(zv0, wzb.w, hbb.w)), 0.f);
            h1v[0] = fmaxf(fmaf(xv1, wxa.x, fmaf(zv1, wza.x, hba.x)), 0.f);
            h1v[1] = fmaxf(fmaf(xv1, wxa.y, fmaf(zv1, wza.y, hba.y)), 0.f);
            h1v[2] = fmaxf(fmaf(xv1, wxa.z, fmaf(zv1, wza.z, hba.z)), 0.f);
            h1v[3] = fmaxf(fmaf(xv1, wxa.w, fmaf(zv1, wza.w, hba.w)), 0.f);
            h1v[4] = fmaxf(fmaf(xv1, wxb.x, fmaf(zv1, wzb.x, hbb.x)), 0.f);
            h1v[5] = fmaxf(fmaf(xv1, wxb.y, fmaf(zv1, wzb.y, hbb.y)), 0.f);
            h1v[6] = fmaxf(fmaf(xv1, wxb.z, fmaf(zv1, wzb.z, hbb.z)), 0.f);
            h1v[7] = fmaxf(fmaf(xv1, wxb.w, fmaf(zv1, wzb.w, hbb.w)), 0.f);

            FragU a0, a1, bf;
            a0.u[0] = pack_bf16(h0[0], h0[1]);
            a0.u[1] = pack_bf16(h0[2], h0[3]);
            a0.u[2] = pack_bf16(h0[4], h0[5]);
            a0.u[3] = pack_bf16(h0[6], h0[7]);
            a1.u[0] = pack_bf16(h1v[0], h1v[1]);
            a1.u[1] = pack_bf16(h1v[2], h1v[3]);
            a1.u[2] = pack_bf16(h1v[4], h1v[5]);
            a1.u[3] = pack_bf16(h1v[6], h1v[7]);
            bf.u[0] = realB ? sh.ia.s.lpw1[pBl][0][jj] : 0u;
            bf.u[1] = realB ? sh.ia.s.lpw1[pBl][1][jj] : 0u;
            bf.u[2] = realB ? sh.ia.s.lpw1[pBl][2][jj] : 0u;
            bf.u[3] = realB ? sh.ia.s.lpw1[pBl][3][jj] : 0u;

            const float pbv = sh.ia.s.lpb[pBl][jj];
            const float w2v = sh.ia.s.lpw2[pBl][jj];

            f32x16 cpb;
            #pragma unroll
            for (int r = 0; r < 16; ++r) cpb[r] = pbv;

            f32x16 d0 = __builtin_amdgcn_mfma_f32_32x32x16_bf16(a0.v, bf.v, cpb, 0, 0, 0);
            f32x16 d1 = __builtin_amdgcn_mfma_f32_32x32x16_bf16(a1.v, bf.v, cpb, 0, 0, 0);

            #pragma unroll
            for (int r = 0; r < 16; ++r)
                acc0[r] = fmaf(fmaxf(d0[r], 0.f), w2v, acc0[r]);
            #pragma unroll
            for (int r = 0; r < 16; ++r)
                acc1[r] = fmaf(fmaxf(d1[r], 0.f), w2v, acc1[r]);
        }

        __syncthreads();   // staging LDS dead; red aliases it from here on
        // phased reduction: waves 0,1 write; waves 2,3 accumulate
        const int rb0 = (w & 1) * 64;
        if (w < 2) {
            #pragma unroll
            for (int r = 0; r < 16; ++r) {
                int rowf = (r & 3) + 8 * (r >> 2) + 4 * kh;
                sh.ia.red[rb0 + rowf][m]      = acc0[r];
                sh.ia.red[rb0 + 32 + rowf][m] = acc1[r];
            }
        }
        __syncthreads();
        if (w >= 2) {
            #pragma unroll
            for (int r = 0; r < 16; ++r) {
                int rowf = (r & 3) + 8 * (r >> 2) + 4 * kh;
                sh.ia.red[rb0 + rowf][m]      += acc0[r];
                sh.ia.red[rb0 + 32 + rowf][m] += acc1[r];
            }
        }
        __syncthreads();
        if (t < 128) {
            float s = 0.f;
            #pragma unroll
            for (int c = 0; c < 32; ++c) s += sh.ia.red[t][c];
            atomicAdd(out + b0 + t, s);
        }
    } else {
        // --------------------------- main-MLP role ---------------------------
        const int r2    = bid;
        const int btile = r2 & 127;
        const int hf    = (r2 >> 7) & 1;
        const int which = (r2 >> 8) & 1;
        const float* in = which ? z   : x;
        const float* w1 = which ? zw1 : xw1;
        const float* b1 = which ? zb1 : xb1;
        const float* w2 = which ? zw2 : xw2;
        const float* b2 = which ? zb2 : xb2;
        const float* w3 = which ? zw3 : xw3;
        const float* b3 = which ? zb3 : xb3;

        const int wu = __builtin_amdgcn_readfirstlane(w);
        const int b0 = btile * 64;

        // input row in registers
        float xr[32];
        const float4* xrp = reinterpret_cast<const float4*>(in + (size_t)(b0 + lane) * 32);
        #pragma unroll
        for (int q = 0; q < 8; ++q) {
            float4 v = xrp[q];
            xr[4*q] = v.x; xr[4*q+1] = v.y; xr[4*q+2] = v.z; xr[4*q+3] = v.w;
        }

        const int n0 = __builtin_amdgcn_readfirstlane(hf*32 + wu*8);
        float h2[8];
        #pragma unroll
        for (int n = 0; n < 8; ++n) h2[n] = b2[n0 + n];

        // two j-halves: phase A computes 16 j per wave, phase B consumes
        #pragma unroll
        for (int half = 0; half < 2; ++half) {
            const int j0 = half*64 + wu*16;
            float h1[16];
            #pragma unroll
            for (int j = 0; j < 16; ++j) h1[j] = b1[j0 + j];
            #pragma unroll
            for (int mm = 0; mm < 32; ++mm) {
                float xv = xr[mm];
                #pragma unroll
                for (int j = 0; j < 16; ++j)
                    h1[j] = fmaf(xv, w1[mm*H1 + j0 + j], h1[j]);
            }
            __syncthreads();   // protect h1T reuse from previous half's reads
            #pragma unroll
            for (int j = 0; j < 16; ++j)
                sh.mm.h1T[wu*16 + j][lane] = fmaxf(h1[j], 0.f);
            __syncthreads();
            #pragma unroll 4
            for (int mm = 0; mm < 64; ++mm) {
                float hv = sh.mm.h1T[mm][lane];
                #pragma unroll
                for (int n = 0; n < 8; ++n)
                    h2[n] = fmaf(hv, w2[(half*64 + mm)*H2 + n0 + n], h2[n]);
            }
        }
        float p = 0.f;
        #pragma unroll
        for (int n = 0; n < 8; ++n)
            p = fmaf(fmaxf(h2[n], 0.f), w3[n0 + n], p);

        sh.mm.red2[wu][lane] = p;
        __syncthreads();
        if (wu == 0) {
            float s = sh.mm.red2[0][lane] + sh.mm.red2[1][lane]
                    + sh.mm.red2[2][lane] + sh.mm.red2[3][lane];
            if (hf == 0) s += b3[0];
            atomicAdd(out + b0 + lane, s);
        }
    }
}

extern "C" void kernel_launch(void* const* d_in, const int* in_sizes, int n_in,
                              void* d_out, int out_size, void* d_ws, size_t ws_size,
                              hipStream_t stream) {
    const float* x   = (const float*)d_in[0];
    const float* z   = (const float*)d_in[1];
    const float* xw1 = (const float*)d_in[2];
    const float* xb1 = (const float*)d_in[3];
    const float* xw2 = (const float*)d_in[4];
    const float* xb2 = (const float*)d_in[5];
    const float* xw3 = (const float*)d_in[6];
    const float* xb3 = (const float*)d_in[7];
    const float* zw1 = (const float*)d_in[8];
    const float* zb1 = (const float*)d_in[9];
    const float* zw2 = (const float*)d_in[10];
    const float* zb2 = (const float*)d_in[11];
    const float* zw3 = (const float*)d_in[12];
    const float* zb3 = (const float*)d_in[13];
    const float* xzw = (const float*)d_in[14];
    const float* xzb = (const float*)d_in[15];
    const float* pw1 = (const float*)d_in[16];
    const float* pb1 = (const float*)d_in[17];
    const float* pw2 = (const float*)d_in[18];
    float* out = (float*)d_out;

    hipMemsetAsync(out, 0, (size_t)out_size * sizeof(float), stream);

    fused_k<<<dim3(NBLK_IA + NBLK_MM), 256, 0, stream>>>(
        x, z, xw1, xb1, xw2, xb2, xw3, xb3,
        zw1, zb1, zw2, zb2, zw3, zb3,
        xzw, xzb, pw1, pb1, pw2, out);
}